// Round 1
// 319.553 us; speedup vs baseline: 1.0201x; 1.0201x over previous
//
#include <hip/hip_runtime.h>
#include <hip/hip_fp16.h>

// GRU cell, B=65536, 256 inputs, 256 hidden, fp32 in/out.
// R4: latency-hiding pass. Evidence: 154us vs ~25us MFMA floor / ~34us HBM
// floor, MfmaUtil 13.7%, VALUBusy 24%, HBM 17% -> stall-bound, not BW-bound.
// VGPR=104 == accz+accr(64)+afrag(16)+wfrag(16)+addr: zero prefetch headroom,
// and 5 __syncthreads each drain vmcnt(0) killing any in-flight loads.
// Changes: (1) depth-1 register double-buffer on weight frags, step-0 issued
// before staging; (2) lgkmcnt-only barriers (raw s_barrier) -- all cross-wave
// hazards are LDS-only, so pass-2 weight/bias prefetch survives the epilogue-1
// barrier; (3) epilogue-2 stores direct to global (drop lout bounce: -2
// barriers, -LDS roundtrip), nontemporal to protect weight L2 residency;
// (4) setprio around MFMA clusters. launch_bounds(512,4) pins VGPR<=128 so
// 2 blocks/CU (4 waves/SIMD) residency is preserved.

#define NHID 256
#define B_ROWS 65536
#define MT 64                        // rows per block
#define RT 4                         // row tiles per wave (MT/16)
#define CPW 2                        // coltiles per wave (16 coltiles / 8 waves)
#define GATE_STRIDE (16 * 16 * 64 * 8)   // halves per packed gate

typedef _Float16 half8 __attribute__((ext_vector_type(8)));
typedef _Float16 half4_t __attribute__((ext_vector_type(4)));
typedef _Float16 half2_t __attribute__((ext_vector_type(2)));
typedef float floatx4 __attribute__((ext_vector_type(4)));

// LDS layout for lx/lh: row-major [MT][256] halves, 8-half-chunk XOR swizzle
__device__ __forceinline__ int lidx(int m, int c) {
    return m * 256 + ((((c >> 3) ^ (m & 7)) << 3)) + (c & 7);
}

// Workgroup barrier that waits only on LDS ops (lgkmcnt), NOT vmcnt -- keeps
// prefetched global loads in flight across phase boundaries. All cross-wave
// dependencies at these points are through LDS, so this is sufficient.
__device__ __forceinline__ void barrier_lgkm() {
    __builtin_amdgcn_sched_barrier(0);
    asm volatile("s_waitcnt lgkmcnt(0)" ::: "memory");
    __builtin_amdgcn_s_barrier();
    __builtin_amdgcn_sched_barrier(0);
}

// ---------- weight packing: B-fragment layout for mfma_f32_16x16x32_f16 ----
// frag (gate g, coltile ct, ktile s): lane holds B[k=s*32+(lane>>4)*8+j][n=ct*16+(lane&15)]
__global__ __launch_bounds__(256) void pack_weights_kernel(
    const float* __restrict__ Wz, const float* __restrict__ Uz,
    const float* __restrict__ Wr, const float* __restrict__ Ur,
    const float* __restrict__ Wh, const float* __restrict__ Uh,
    _Float16* __restrict__ packed)
{
    int tid = blockIdx.x * blockDim.x + threadIdx.x;  // 0..49151
    int lane = tid & 63;
    int s    = (tid >> 6) & 15;
    int ct   = (tid >> 10) & 15;
    int g    = tid >> 14;  // 0:z 1:r 2:h
    const float* W = (g == 0) ? Wz : (g == 1) ? Wr : Wh;
    const float* U = (g == 0) ? Uz : (g == 1) ? Ur : Uh;
    int n  = ct * 16 + (lane & 15);
    int k0 = s * 32 + (lane >> 4) * 8;
    half8 v;
#pragma unroll
    for (int j = 0; j < 8; ++j) {
        int k = k0 + j;
        float f = (k < 256) ? W[k * 256 + n] : U[(k - 256) * 256 + n];
        v[j] = (_Float16)f;
    }
    *reinterpret_cast<half8*>(packed + (size_t)tid * 8) = v;
}

// fragment load for (gate base, coltile ct, ktile s)
#define WFRAG(base, ct, s) \
    (*reinterpret_cast<const half8*>((base) + (size_t)((((ct) * 16 + (s)) * 64 + lane) * 8)))

// ---------- main fused GRU kernel ----------
__global__ __launch_bounds__(512, 4) void gru_main_kernel(
    const float* __restrict__ x, const float* __restrict__ h,
    const _Float16* __restrict__ wpack,
    const float* __restrict__ bz, const float* __restrict__ br,
    const float* __restrict__ bh,
    float* __restrict__ out)
{
    // 64 KB: lx[64*256] + lh[64*256] halves -> 2 blocks/CU (128 KB of 160 KB)
    __shared__ __align__(16) _Float16 lsm[MT * 256 * 2];
    _Float16* lx = lsm;
    _Float16* lh = lsm + MT * 256;

    const int tid  = threadIdx.x;
    const int lane = tid & 63;
    const int wave = tid >> 6;        // 0..7, owns coltiles wave*2, wave*2+1
    const int row0 = blockIdx.x * MT;
    const int m_lo = lane & 15;
    const int quad = lane >> 4;
    const int mx   = m_lo & 7;
    const int ct0  = wave * CPW;

    const _Float16* wz = wpack;
    const _Float16* wr = wpack + GATE_STRIDE;
    const _Float16* wh = wpack + 2 * GATE_STRIDE;

    // ---- prefetch pass-1 step-0 weight frags: in flight under the staging
    //      HBM loads and across the lgkm-only staging barrier ----
    half8 wzb[2][CPW], wrb[2][CPW];
    wzb[0][0] = WFRAG(wz, ct0 + 0, 0);
    wzb[0][1] = WFRAG(wz, ct0 + 1, 0);
    wrb[0][0] = WFRAG(wr, ct0 + 0, 0);
    wrb[0][1] = WFRAG(wr, ct0 + 1, 0);

    // ---- stage x, h -> LDS fp16 (16 outstanding 16B loads/thread) ----
    {
        const float4* xv = reinterpret_cast<const float4*>(x + (size_t)row0 * NHID);
        const float4* hv = reinterpret_cast<const float4*>(h + (size_t)row0 * NHID);
#pragma unroll
        for (int it = 0; it < (MT * 64) / 512; ++it) {
            int i = it * 512 + tid;
            int m = i >> 6;
            int c = (i & 63) * 4;
            float4 a = xv[i];
            float4 b = hv[i];
            half4_t va = { (_Float16)a.x, (_Float16)a.y, (_Float16)a.z, (_Float16)a.w };
            half4_t vb = { (_Float16)b.x, (_Float16)b.y, (_Float16)b.z, (_Float16)b.w };
            *reinterpret_cast<half4_t*>(&lx[lidx(m, c)]) = va;
            *reinterpret_cast<half4_t*>(&lh[lidx(m, c)]) = vb;
        }
    }
    barrier_lgkm();

    // packed (z*h, 1-z) per output element, fp16x2 -> 32 VGPRs (live pass2 only)
    half2_t zpk[CPW][RT][4];

    // ---- pass 1: Sz = [x|h]@[Wz;Uz], Sr = [x|h]@[Wr;Ur]  (K=512) ----
    floatx4 accz[CPW][RT];
    floatx4 accr[CPW][RT];
#pragma unroll
    for (int c = 0; c < CPW; ++c)
#pragma unroll
        for (int rt = 0; rt < RT; ++rt) {
            accz[c][rt] = (floatx4){0.f, 0.f, 0.f, 0.f};
            accr[c][rt] = (floatx4){0.f, 0.f, 0.f, 0.f};
        }

#pragma unroll
    for (int s = 0; s < 16; ++s) {
        const int cur = s & 1, nxt = cur ^ 1;   // compile-time under full unroll
        if (s < 15) {
            wzb[nxt][0] = WFRAG(wz, ct0 + 0, s + 1);
            wzb[nxt][1] = WFRAG(wz, ct0 + 1, s + 1);
            wrb[nxt][0] = WFRAG(wr, ct0 + 0, s + 1);
            wrb[nxt][1] = WFRAG(wr, ct0 + 1, s + 1);
        }
        const _Float16* asrc = (s < 8) ? lx : lh;
        const int kcx = (((s & 7) * 4 + quad) ^ mx) << 3;
        half8 af[RT];
#pragma unroll
        for (int rt = 0; rt < RT; ++rt)
            af[rt] = *reinterpret_cast<const half8*>(&asrc[(rt * 16 + m_lo) * 256 + kcx]);
        __builtin_amdgcn_s_setprio(1);
#pragma unroll
        for (int c = 0; c < CPW; ++c)
#pragma unroll
            for (int rt = 0; rt < RT; ++rt) {
                accz[c][rt] = __builtin_amdgcn_mfma_f32_16x16x32_f16(af[rt], wzb[cur][c], accz[c][rt], 0, 0, 0);
                accr[c][rt] = __builtin_amdgcn_mfma_f32_16x16x32_f16(af[rt], wrb[cur][c], accr[c][rt], 0, 0, 0);
            }
        __builtin_amdgcn_s_setprio(0);
    }

    // ---- prefetch pass-2 step-0 weights + all biases: issued before the
    //      barrier, stay in flight through epilogue 1 (lgkm-only barriers) ----
    half8 whb[2][CPW];
    whb[0][0] = WFRAG(wh, ct0 + 0, 0);
    whb[0][1] = WFRAG(wh, ct0 + 1, 0);
    float bzv[CPW], brv[CPW], bhv[CPW];
#pragma unroll
    for (int c = 0; c < CPW; ++c) {
        const int col = (ct0 + c) * 16 + m_lo;
        bzv[c] = bz[col];
        brv[c] = br[col];
        bhv[c] = bh[col];
    }

    barrier_lgkm();  // all waves done reading lh before overwriting with r*h

    // ---- epilogue 1: z, r; lh <- r*h; zpk <- (fp16)(z*h, 1-z) ----
    // C layout: col(tile) = lane&15, row(tile) = quad*4 + reg
#pragma unroll
    for (int c = 0; c < CPW; ++c) {
        const int col = (ct0 + c) * 16 + m_lo;
#pragma unroll
        for (int rt = 0; rt < RT; ++rt) {
#pragma unroll
            for (int e = 0; e < 4; ++e) {
                const int row = rt * 16 + quad * 4 + e;
                float sz = accz[c][rt][e] + bzv[c];
                float sr = accr[c][rt][e] + brv[c];
                float zv = 1.f / (1.f + __expf(-sz));
                float rv = 1.f / (1.f + __expf(-sr));
                const int li = lidx(row, col);
                float hval = (float)lh[li];
                lh[li] = (_Float16)(rv * hval);
                zpk[c][rt][e] = half2_t{ (_Float16)(zv * hval), (_Float16)(1.f - zv) };
            }
        }
    }

    barrier_lgkm();  // r*h visible to all waves

    // ---- pass 2: Sh = [x|r*h]@[Wh;Uh]  (K=512) ----
    floatx4 acch[CPW][RT];
#pragma unroll
    for (int c = 0; c < CPW; ++c)
#pragma unroll
        for (int rt = 0; rt < RT; ++rt)
            acch[c][rt] = (floatx4){0.f, 0.f, 0.f, 0.f};

#pragma unroll
    for (int s = 0; s < 16; ++s) {
        const int cur = s & 1, nxt = cur ^ 1;
        if (s < 15) {
            whb[nxt][0] = WFRAG(wh, ct0 + 0, s + 1);
            whb[nxt][1] = WFRAG(wh, ct0 + 1, s + 1);
        }
        const _Float16* asrc = (s < 8) ? lx : lh;
        const int kcx = (((s & 7) * 4 + quad) ^ mx) << 3;
        half8 af[RT];
#pragma unroll
        for (int rt = 0; rt < RT; ++rt)
            af[rt] = *reinterpret_cast<const half8*>(&asrc[(rt * 16 + m_lo) * 256 + kcx]);
        __builtin_amdgcn_s_setprio(1);
#pragma unroll
        for (int c = 0; c < CPW; ++c)
#pragma unroll
            for (int rt = 0; rt < RT; ++rt)
                acch[c][rt] = __builtin_amdgcn_mfma_f32_16x16x32_f16(af[rt], whb[cur][c], acch[c][rt], 0, 0, 0);
        __builtin_amdgcn_s_setprio(0);
    }

    // ---- epilogue 2: h_t = z*h + (1-z)*tanh(Sh+bh), direct global stores ----
    // No barrier needed: nothing after this touches LDS. Each 16-lane group
    // writes a contiguous 64 B segment; L2 write-combines full lines.
    const size_t OUT2 = (size_t)B_ROWS * NHID;
#pragma unroll
    for (int c = 0; c < CPW; ++c) {
        const int col = (ct0 + c) * 16 + m_lo;
#pragma unroll
        for (int rt = 0; rt < RT; ++rt) {
#pragma unroll
            for (int e = 0; e < 4; ++e) {
                const int row = rt * 16 + quad * 4 + e;
                float sh = acch[c][rt][e] + bhv[c];
                float e2 = __expf(2.f * sh);
                float hh = 1.f - 2.f / (e2 + 1.f);  // tanh
                float zh  = (float)zpk[c][rt][e][0];
                float omz = (float)zpk[c][rt][e][1];
                float ht  = zh + omz * hh;
                size_t idx = (size_t)(row0 + row) * NHID + col;
                __builtin_nontemporal_store(ht, &out[idx]);
                __builtin_nontemporal_store(ht, &out[OUT2 + idx]);
            }
        }
    }
}

extern "C" void kernel_launch(void* const* d_in, const int* in_sizes, int n_in,
                              void* d_out, int out_size, void* d_ws, size_t ws_size,
                              hipStream_t stream) {
    (void)in_sizes; (void)n_in; (void)out_size; (void)ws_size;
    const float* x  = (const float*)d_in[0];
    const float* h  = (const float*)d_in[1];
    const float* Wz = (const float*)d_in[2];
    const float* Uz = (const float*)d_in[3];
    const float* bz = (const float*)d_in[4];
    const float* Wr = (const float*)d_in[5];
    const float* Ur = (const float*)d_in[6];
    const float* br = (const float*)d_in[7];
    const float* Wh = (const float*)d_in[8];
    const float* Uh = (const float*)d_in[9];
    const float* bh = (const float*)d_in[10];
    float* out = (float*)d_out;
    _Float16* wpack = (_Float16*)d_ws;  // 3*512*256*2 = 768 KB

    pack_weights_kernel<<<192, 256, 0, stream>>>(Wz, Uz, Wr, Ur, Wh, Uh, wpack);
    gru_main_kernel<<<B_ROWS / MT, 512, 0, stream>>>(x, h, wpack, bz, br, bh, out);
}

// Round 2
// 312.102 us; speedup vs baseline: 1.0445x; 1.0239x over previous
//
#include <hip/hip_runtime.h>
#include <hip/hip_fp16.h>

// GRU cell, B=65536, 256 inputs, 256 hidden, fp32 in/out.
// R5 = R4 with the launch-bounds bug fixed. R4's __launch_bounds__(512,4)
// made the compiler allocate 64 VGPRs and spill ~284 B/thread (FETCH +70MB,
// WRITE +149MB) -- the dbuf/lgkm-barrier experiment never ran. Key R4
// measurement preserved: +220MB of spill traffic did NOT change duration
// (154->157us), proving huge latency slack -- the kernel is stall-bound,
// not BW-bound. R5 restores (512,2) (R3 measured 104 VGPR, no spill; this
// version's +16 VGPR of weight dbuf lands ~120 <= 128, keeping 2 blocks/CU,
// 4 waves/SIMD).
// Retained from R4:
// (1) depth-1 register double-buffer on weight frags, step-0 issued before
//     staging so it flies under the HBM loads;
// (2) lgkmcnt-only barriers (raw s_barrier) -- all cross-wave hazards are
//     LDS-only, so pass-2 weight/bias prefetch stays in flight across the
//     epilogue-1 barrier (no vmcnt(0) drains anywhere in the body);
// (3) epilogue-2 stores direct to global (drop lout bounce: -2 barriers,
//     -LDS roundtrip), nontemporal to protect weight L2 residency;
// (4) setprio around MFMA clusters.

#define NHID 256
#define B_ROWS 65536
#define MT 64                        // rows per block
#define RT 4                         // row tiles per wave (MT/16)
#define CPW 2                        // coltiles per wave (16 coltiles / 8 waves)
#define GATE_STRIDE (16 * 16 * 64 * 8)   // halves per packed gate

typedef _Float16 half8 __attribute__((ext_vector_type(8)));
typedef _Float16 half4_t __attribute__((ext_vector_type(4)));
typedef _Float16 half2_t __attribute__((ext_vector_type(2)));
typedef float floatx4 __attribute__((ext_vector_type(4)));

// LDS layout for lx/lh: row-major [MT][256] halves, 8-half-chunk XOR swizzle
__device__ __forceinline__ int lidx(int m, int c) {
    return m * 256 + ((((c >> 3) ^ (m & 7)) << 3)) + (c & 7);
}

// Workgroup barrier that waits only on LDS ops (lgkmcnt), NOT vmcnt -- keeps
// prefetched global loads in flight across phase boundaries. All cross-wave
// dependencies at these points are through LDS, so this is sufficient.
__device__ __forceinline__ void barrier_lgkm() {
    __builtin_amdgcn_sched_barrier(0);
    asm volatile("s_waitcnt lgkmcnt(0)" ::: "memory");
    __builtin_amdgcn_s_barrier();
    __builtin_amdgcn_sched_barrier(0);
}

// ---------- weight packing: B-fragment layout for mfma_f32_16x16x32_f16 ----
// frag (gate g, coltile ct, ktile s): lane holds B[k=s*32+(lane>>4)*8+j][n=ct*16+(lane&15)]
__global__ __launch_bounds__(256) void pack_weights_kernel(
    const float* __restrict__ Wz, const float* __restrict__ Uz,
    const float* __restrict__ Wr, const float* __restrict__ Ur,
    const float* __restrict__ Wh, const float* __restrict__ Uh,
    _Float16* __restrict__ packed)
{
    int tid = blockIdx.x * blockDim.x + threadIdx.x;  // 0..49151
    int lane = tid & 63;
    int s    = (tid >> 6) & 15;
    int ct   = (tid >> 10) & 15;
    int g    = tid >> 14;  // 0:z 1:r 2:h
    const float* W = (g == 0) ? Wz : (g == 1) ? Wr : Wh;
    const float* U = (g == 0) ? Uz : (g == 1) ? Ur : Uh;
    int n  = ct * 16 + (lane & 15);
    int k0 = s * 32 + (lane >> 4) * 8;
    half8 v;
#pragma unroll
    for (int j = 0; j < 8; ++j) {
        int k = k0 + j;
        float f = (k < 256) ? W[k * 256 + n] : U[(k - 256) * 256 + n];
        v[j] = (_Float16)f;
    }
    *reinterpret_cast<half8*>(packed + (size_t)tid * 8) = v;
}

// fragment load for (gate base, coltile ct, ktile s)
#define WFRAG(base, ct, s) \
    (*reinterpret_cast<const half8*>((base) + (size_t)((((ct) * 16 + (s)) * 64 + lane) * 8)))

// ---------- main fused GRU kernel ----------
__global__ __launch_bounds__(512, 2) void gru_main_kernel(
    const float* __restrict__ x, const float* __restrict__ h,
    const _Float16* __restrict__ wpack,
    const float* __restrict__ bz, const float* __restrict__ br,
    const float* __restrict__ bh,
    float* __restrict__ out)
{
    // 64 KB: lx[64*256] + lh[64*256] halves -> 2 blocks/CU (128 KB of 160 KB)
    __shared__ __align__(16) _Float16 lsm[MT * 256 * 2];
    _Float16* lx = lsm;
    _Float16* lh = lsm + MT * 256;

    const int tid  = threadIdx.x;
    const int lane = tid & 63;
    const int wave = tid >> 6;        // 0..7, owns coltiles wave*2, wave*2+1
    const int row0 = blockIdx.x * MT;
    const int m_lo = lane & 15;
    const int quad = lane >> 4;
    const int mx   = m_lo & 7;
    const int ct0  = wave * CPW;

    const _Float16* wz = wpack;
    const _Float16* wr = wpack + GATE_STRIDE;
    const _Float16* wh = wpack + 2 * GATE_STRIDE;

    // ---- prefetch pass-1 step-0 weight frags: in flight under the staging
    //      HBM loads and across the lgkm-only staging barrier ----
    half8 wzb[2][CPW], wrb[2][CPW];
    wzb[0][0] = WFRAG(wz, ct0 + 0, 0);
    wzb[0][1] = WFRAG(wz, ct0 + 1, 0);
    wrb[0][0] = WFRAG(wr, ct0 + 0, 0);
    wrb[0][1] = WFRAG(wr, ct0 + 1, 0);

    // ---- stage x, h -> LDS fp16 (16 outstanding 16B loads/thread) ----
    {
        const float4* xv = reinterpret_cast<const float4*>(x + (size_t)row0 * NHID);
        const float4* hv = reinterpret_cast<const float4*>(h + (size_t)row0 * NHID);
#pragma unroll
        for (int it = 0; it < (MT * 64) / 512; ++it) {
            int i = it * 512 + tid;
            int m = i >> 6;
            int c = (i & 63) * 4;
            float4 a = xv[i];
            float4 b = hv[i];
            half4_t va = { (_Float16)a.x, (_Float16)a.y, (_Float16)a.z, (_Float16)a.w };
            half4_t vb = { (_Float16)b.x, (_Float16)b.y, (_Float16)b.z, (_Float16)b.w };
            *reinterpret_cast<half4_t*>(&lx[lidx(m, c)]) = va;
            *reinterpret_cast<half4_t*>(&lh[lidx(m, c)]) = vb;
        }
    }
    barrier_lgkm();

    // packed (z*h, 1-z) per output element, fp16x2 -> 32 VGPRs (live pass2 only)
    half2_t zpk[CPW][RT][4];

    // ---- pass 1: Sz = [x|h]@[Wz;Uz], Sr = [x|h]@[Wr;Ur]  (K=512) ----
    floatx4 accz[CPW][RT];
    floatx4 accr[CPW][RT];
#pragma unroll
    for (int c = 0; c < CPW; ++c)
#pragma unroll
        for (int rt = 0; rt < RT; ++rt) {
            accz[c][rt] = (floatx4){0.f, 0.f, 0.f, 0.f};
            accr[c][rt] = (floatx4){0.f, 0.f, 0.f, 0.f};
        }

#pragma unroll
    for (int s = 0; s < 16; ++s) {
        const int cur = s & 1, nxt = cur ^ 1;   // compile-time under full unroll
        if (s < 15) {
            wzb[nxt][0] = WFRAG(wz, ct0 + 0, s + 1);
            wzb[nxt][1] = WFRAG(wz, ct0 + 1, s + 1);
            wrb[nxt][0] = WFRAG(wr, ct0 + 0, s + 1);
            wrb[nxt][1] = WFRAG(wr, ct0 + 1, s + 1);
        }
        const _Float16* asrc = (s < 8) ? lx : lh;
        const int kcx = (((s & 7) * 4 + quad) ^ mx) << 3;
        half8 af[RT];
#pragma unroll
        for (int rt = 0; rt < RT; ++rt)
            af[rt] = *reinterpret_cast<const half8*>(&asrc[(rt * 16 + m_lo) * 256 + kcx]);
        __builtin_amdgcn_s_setprio(1);
#pragma unroll
        for (int c = 0; c < CPW; ++c)
#pragma unroll
            for (int rt = 0; rt < RT; ++rt) {
                accz[c][rt] = __builtin_amdgcn_mfma_f32_16x16x32_f16(af[rt], wzb[cur][c], accz[c][rt], 0, 0, 0);
                accr[c][rt] = __builtin_amdgcn_mfma_f32_16x16x32_f16(af[rt], wrb[cur][c], accr[c][rt], 0, 0, 0);
            }
        __builtin_amdgcn_s_setprio(0);
    }

    // ---- prefetch pass-2 step-0 weights + all biases: issued before the
    //      barrier, stay in flight through epilogue 1 (lgkm-only barriers) ----
    half8 whb[2][CPW];
    whb[0][0] = WFRAG(wh, ct0 + 0, 0);
    whb[0][1] = WFRAG(wh, ct0 + 1, 0);
    float bzv[CPW], brv[CPW], bhv[CPW];
#pragma unroll
    for (int c = 0; c < CPW; ++c) {
        const int col = (ct0 + c) * 16 + m_lo;
        bzv[c] = bz[col];
        brv[c] = br[col];
        bhv[c] = bh[col];
    }

    barrier_lgkm();  // all waves done reading lh before overwriting with r*h

    // ---- epilogue 1: z, r; lh <- r*h; zpk <- (fp16)(z*h, 1-z) ----
    // C layout: col(tile) = lane&15, row(tile) = quad*4 + reg
#pragma unroll
    for (int c = 0; c < CPW; ++c) {
        const int col = (ct0 + c) * 16 + m_lo;
#pragma unroll
        for (int rt = 0; rt < RT; ++rt) {
#pragma unroll
            for (int e = 0; e < 4; ++e) {
                const int row = rt * 16 + quad * 4 + e;
                float sz = accz[c][rt][e] + bzv[c];
                float sr = accr[c][rt][e] + brv[c];
                float zv = 1.f / (1.f + __expf(-sz));
                float rv = 1.f / (1.f + __expf(-sr));
                const int li = lidx(row, col);
                float hval = (float)lh[li];
                lh[li] = (_Float16)(rv * hval);
                zpk[c][rt][e] = half2_t{ (_Float16)(zv * hval), (_Float16)(1.f - zv) };
            }
        }
    }

    barrier_lgkm();  // r*h visible to all waves

    // ---- pass 2: Sh = [x|r*h]@[Wh;Uh]  (K=512) ----
    floatx4 acch[CPW][RT];
#pragma unroll
    for (int c = 0; c < CPW; ++c)
#pragma unroll
        for (int rt = 0; rt < RT; ++rt)
            acch[c][rt] = (floatx4){0.f, 0.f, 0.f, 0.f};

#pragma unroll
    for (int s = 0; s < 16; ++s) {
        const int cur = s & 1, nxt = cur ^ 1;
        if (s < 15) {
            whb[nxt][0] = WFRAG(wh, ct0 + 0, s + 1);
            whb[nxt][1] = WFRAG(wh, ct0 + 1, s + 1);
        }
        const _Float16* asrc = (s < 8) ? lx : lh;
        const int kcx = (((s & 7) * 4 + quad) ^ mx) << 3;
        half8 af[RT];
#pragma unroll
        for (int rt = 0; rt < RT; ++rt)
            af[rt] = *reinterpret_cast<const half8*>(&asrc[(rt * 16 + m_lo) * 256 + kcx]);
        __builtin_amdgcn_s_setprio(1);
#pragma unroll
        for (int c = 0; c < CPW; ++c)
#pragma unroll
            for (int rt = 0; rt < RT; ++rt)
                acch[c][rt] = __builtin_amdgcn_mfma_f32_16x16x32_f16(af[rt], whb[cur][c], acch[c][rt], 0, 0, 0);
        __builtin_amdgcn_s_setprio(0);
    }

    // ---- epilogue 2: h_t = z*h + (1-z)*tanh(Sh+bh), direct global stores ----
    // No barrier needed: nothing after this touches LDS. Each 16-lane group
    // writes a contiguous 64 B segment; L2 write-combines adjacent segments
    // (WRITE_SIZE must stay ~131072 KB -- if it balloons, revert to bounce).
    const size_t OUT2 = (size_t)B_ROWS * NHID;
#pragma unroll
    for (int c = 0; c < CPW; ++c) {
        const int col = (ct0 + c) * 16 + m_lo;
#pragma unroll
        for (int rt = 0; rt < RT; ++rt) {
#pragma unroll
            for (int e = 0; e < 4; ++e) {
                const int row = rt * 16 + quad * 4 + e;
                float sh = acch[c][rt][e] + bhv[c];
                float e2 = __expf(2.f * sh);
                float hh = 1.f - 2.f / (e2 + 1.f);  // tanh
                float zh  = (float)zpk[c][rt][e][0];
                float omz = (float)zpk[c][rt][e][1];
                float ht  = zh + omz * hh;
                size_t idx = (size_t)(row0 + row) * NHID + col;
                __builtin_nontemporal_store(ht, &out[idx]);
                __builtin_nontemporal_store(ht, &out[OUT2 + idx]);
            }
        }
    }
}

extern "C" void kernel_launch(void* const* d_in, const int* in_sizes, int n_in,
                              void* d_out, int out_size, void* d_ws, size_t ws_size,
                              hipStream_t stream) {
    (void)in_sizes; (void)n_in; (void)out_size; (void)ws_size;
    const float* x  = (const float*)d_in[0];
    const float* h  = (const float*)d_in[1];
    const float* Wz = (const float*)d_in[2];
    const float* Uz = (const float*)d_in[3];
    const float* bz = (const float*)d_in[4];
    const float* Wr = (const float*)d_in[5];
    const float* Ur = (const float*)d_in[6];
    const float* br = (const float*)d_in[7];
    const float* Wh = (const float*)d_in[8];
    const float* Uh = (const float*)d_in[9];
    const float* bh = (const float*)d_in[10];
    float* out = (float*)d_out;
    _Float16* wpack = (_Float16*)d_ws;  // 3*512*256*2 = 768 KB

    pack_weights_kernel<<<192, 256, 0, stream>>>(Wz, Uz, Wr, Ur, Wh, Uh, wpack);
    gru_main_kernel<<<B_ROWS / MT, 512, 0, stream>>>(x, h, wpack, bz, br, bh, out);
}